// Round 2
// baseline (753.140 us; speedup 1.0000x reference)
//
#include <hip/hip_runtime.h>
#include <math.h>

typedef float f4 __attribute__((ext_vector_type(4)));
typedef float f2 __attribute__((ext_vector_type(2)));

#define NUM_G 64
#define CH 16          // per-graph chunks for deterministic partial reductions
#define EPSV 1e-5f

__device__ inline f4 f4_max(f4 a, f4 b) {
  f4 r;
#pragma unroll
  for (int i = 0; i < 4; ++i) r[i] = fmaxf(a[i], b[i]);
  return r;
}

// ---------------- init: deg=1 (self loop), ecnt=0, graph start offsets ----------------
__global__ void k_init(const int* __restrict__ batch, float* __restrict__ deg,
                       int* __restrict__ ecnt, int* __restrict__ gstart, int N) {
  int n = blockIdx.x * blockDim.x + threadIdx.x;
  if (n >= N) return;
  deg[n] = 1.0f;
  ecnt[n] = 0;
  int bn = batch[n];
  int bp = (n == 0) ? -1 : batch[n - 1];
  for (int g = bp + 1; g <= bn; ++g) gstart[g] = n;
  if (n == N - 1) {
    for (int g = bn + 1; g <= NUM_G; ++g) gstart[g] = N;
  }
}

// ---------------- weighted in-degree + edge count histogram ----------------
__global__ void k_deg(const int* __restrict__ col, const float* __restrict__ ew,
                      float* __restrict__ deg, int* __restrict__ ecnt, int E) {
  int e = blockIdx.x * blockDim.x + threadIdx.x;
  if (e >= E) return;
  int c = col[e];
  atomicAdd(&deg[c], ew[e]);
  atomicAdd(&ecnt[c], 1);
}

// ---------------- single-block exclusive scan of ecnt -> off,cursor; dis = rsqrt(deg) ----------------
__global__ __launch_bounds__(1024) void k_scan(const int* __restrict__ ecnt,
                                               const float* __restrict__ deg,
                                               int* __restrict__ off, int* __restrict__ cursor,
                                               float* __restrict__ dis, int N) {
  __shared__ int sb[1024];
  int tid = threadIdx.x;
  int chunk = (N + 1023) >> 10;
  int s = tid * chunk;
  int e = min(s + chunk, N);
  int local = 0;
  int n = s;
  for (; n + 4 <= e; n += 4)
    local += ecnt[n] + ecnt[n + 1] + ecnt[n + 2] + ecnt[n + 3];
  for (; n < e; ++n) local += ecnt[n];
  sb[tid] = local;
  __syncthreads();
  for (int o = 1; o < 1024; o <<= 1) {
    int v = sb[tid];
    int add = (tid >= o) ? sb[tid - o] : 0;
    __syncthreads();
    sb[tid] = v + add;
    __syncthreads();
  }
  if (tid == 0) off[N] = sb[1023];
  int running = sb[tid] - local;
  for (n = s; n < e; ++n) {
    off[n] = running;
    cursor[n] = running;
    running += ecnt[n];
    float d = deg[n];
    dis[n] = (d > 0.f) ? (1.0f / sqrtf(d)) : 0.f;
  }
}

// ---------------- GEMM: x = inputs @ W  (fp32 VALU, W staged in LDS) ----------------
__global__ __launch_bounds__(256) void k_gemm(const float* __restrict__ in,
                                              const float* __restrict__ Wg,
                                              float* __restrict__ x, int N, int ntiles) {
  __shared__ float Wl[128 * 128];  // 64 KiB
  f4* Wl4 = (f4*)Wl;
  const f4* Wg4 = (const f4*)Wg;
  for (int i = threadIdx.x; i < 4096; i += 256) Wl4[i] = Wg4[i];
  __syncthreads();
  int lane = threadIdx.x & 31;  // col group: cols 4*lane..4*lane+3
  int rp = threadIdx.x >> 5;    // 0..7 -> row pair within 16-row tile
  int cg = lane * 4;
  for (int tile = blockIdx.x; tile < ntiles; tile += gridDim.x) {
    int r0 = tile * 16 + rp * 2;
    int r1 = r0 + 1;
    bool ok0 = r0 < N, ok1 = r1 < N;
    const f4* a0p = (const f4*)(in + (size_t)(ok0 ? r0 : 0) * 128);
    const f4* a1p = (const f4*)(in + (size_t)(ok1 ? r1 : 0) * 128);
    f4 acc0 = (f4)0.f, acc1 = (f4)0.f;
#pragma unroll 4
    for (int k4 = 0; k4 < 32; ++k4) {
      f4 a0 = a0p[k4];
      f4 a1 = a1p[k4];
      int kb = k4 * 4;
#pragma unroll
      for (int kk = 0; kk < 4; ++kk) {
        f4 wv = Wl4[((kb + kk) * 128 + cg) >> 2];
        acc0 += a0[kk] * wv;
        acc1 += a1[kk] * wv;
      }
    }
    if (ok0) ((f4*)(x + (size_t)r0 * 128))[lane] = acc0;
    if (ok1) ((f4*)(x + (size_t)r1 * 128))[lane] = acc1;
  }
}

// ---------------- counting-sort scatter: build CSR-by-target (srow, snorm) ----------------
__global__ void k_scatter(const int* __restrict__ row, const int* __restrict__ col,
                          const float* __restrict__ ew, const float* __restrict__ dis,
                          int* __restrict__ cursor, int* __restrict__ srow,
                          float* __restrict__ snorm, int E) {
  int e = blockIdx.x * blockDim.x + threadIdx.x;
  if (e >= E) return;
  int r = row[e], c = col[e];
  float nm = dis[r] * ew[e] * dis[c];
  int p = atomicAdd(&cursor[c], 1);
  srow[p] = r;
  snorm[p] = nm;
}

// ---------------- per-node gather-accumulate: out = sum(msg) + selfloop + bias ----------------
// one node per 64-lane wave (f2/lane = 128 feats); 4 waves (nodes) per block
__global__ __launch_bounds__(256) void k_accum(const float* __restrict__ x,
                                               const float* __restrict__ dis,
                                               const int* __restrict__ off,
                                               const int* __restrict__ srow,
                                               const float* __restrict__ snorm,
                                               const float* __restrict__ bias,
                                               float* __restrict__ out, int N) {
  int lane = threadIdx.x & 63;  // 64 lanes x float2 = 128 features
  int sub = threadIdx.x >> 6;   // 4 nodes per block
  int n = blockIdx.x * 4 + sub;
  if (n >= N) return;
  const f2* x2 = (const f2*)x;
  float dn = dis[n];
  f2 acc0 = x2[(size_t)n * 64 + lane] * (dn * dn);  // self-loop: norm = dis[n]^2
  f2 acc1 = (f2)0.f;
  int s = off[n], e = off[n + 1];
  int i = s;
  for (; i + 2 <= e; i += 2) {  // 2-deep MLP on the random row gathers
    int r0 = srow[i], r1 = srow[i + 1];
    float nm0 = snorm[i], nm1 = snorm[i + 1];
    f2 v0 = x2[(size_t)r0 * 64 + lane];
    f2 v1 = x2[(size_t)r1 * 64 + lane];
    acc0 += v0 * nm0;
    acc1 += v1 * nm1;
  }
  if (i < e) acc0 += x2[(size_t)srow[i] * 64 + lane] * snorm[i];
  acc0 += acc1 + ((const f2*)bias)[lane];
  ((f2*)out)[(size_t)n * 64 + lane] = acc0;
}

// ---------------- GraphNorm pass 1: partial sums per (graph, chunk) ----------------
__global__ __launch_bounds__(256) void k_mean_p(const float* __restrict__ out,
                                                const int* __restrict__ gstart,
                                                float* __restrict__ Smean) {
  int g = blockIdx.x / CH, c = blockIdx.x % CH;
  int s = gstart[g], e = gstart[g + 1];
  int len = e - s;
  int csz = (len + CH - 1) / CH;
  int r0 = s + c * csz, r1 = min(r0 + csz, e);
  int lane = threadIdx.x & 31, rg = threadIdx.x >> 5;
  const f4* out4 = (const f4*)out;
  f4 acc = (f4)0.f;
  for (int r = r0 + rg; r < r1; r += 8) acc += out4[(size_t)r * 32 + lane];
  __shared__ f4 red[256];
  red[threadIdx.x] = acc;
  __syncthreads();
  for (int st = 4; st >= 1; st >>= 1) {
    if (rg < st) red[threadIdx.x] += red[threadIdx.x + st * 32];
    __syncthreads();
  }
  if (rg == 0) ((f4*)Smean)[(size_t)(g * CH + c) * 32 + lane] = red[threadIdx.x];
}

// ---------------- GraphNorm pass 2: partial var sums ----------------
__global__ __launch_bounds__(256) void k_var_p(const float* __restrict__ out,
                                               const int* __restrict__ gstart,
                                               const float* __restrict__ Smean,
                                               const float* __restrict__ alpha,
                                               float* __restrict__ Svar) {
  int g = blockIdx.x / CH, c = blockIdx.x % CH;
  int s = gstart[g], e = gstart[g + 1];
  int len = e - s;
  float inv_cnt = 1.0f / (float)((len < 1) ? 1 : len);
  __shared__ f4 meanl[32];
  int lane = threadIdx.x & 31, rg = threadIdx.x >> 5;
  if (threadIdx.x < 32) {
    f4 m = (f4)0.f;
    for (int cc = 0; cc < CH; ++cc) m += ((const f4*)Smean)[(size_t)(g * CH + cc) * 32 + threadIdx.x];
    meanl[threadIdx.x] = m * inv_cnt;
  }
  __syncthreads();
  int csz = (len + CH - 1) / CH;
  int r0 = s + c * csz, r1 = min(r0 + csz, e);
  f4 am = ((const f4*)alpha)[lane] * meanl[lane];
  const f4* out4 = (const f4*)out;
  f4 acc = (f4)0.f;
  for (int r = r0 + rg; r < r1; r += 8) {
    f4 sb = out4[(size_t)r * 32 + lane] - am;
    acc += sb * sb;
  }
  __shared__ f4 red[256];
  red[threadIdx.x] = acc;
  __syncthreads();
  for (int st = 4; st >= 1; st >>= 1) {
    if (rg < st) red[threadIdx.x] += red[threadIdx.x + st * 32];
    __syncthreads();
  }
  if (rg == 0) ((f4*)Svar)[(size_t)(g * CH + c) * 32 + lane] = red[threadIdx.x];
}

// ---------------- finalize: h = relu((out-alpha*mean)*invstd*w + b); partial max ----------------
__global__ __launch_bounds__(256) void k_final(float* __restrict__ out,
                                               const int* __restrict__ gstart,
                                               const float* __restrict__ Smean,
                                               const float* __restrict__ Svar,
                                               const float* __restrict__ alpha,
                                               const float* __restrict__ gw,
                                               const float* __restrict__ gb,
                                               float* __restrict__ Pmax) {
  int g = blockIdx.x / CH, c = blockIdx.x % CH;
  int s = gstart[g], e = gstart[g + 1];
  int len = e - s;
  float inv_cnt = 1.0f / (float)((len < 1) ? 1 : len);
  __shared__ f4 meanl[32], istdl[32];
  int lane = threadIdx.x & 31, rg = threadIdx.x >> 5;
  if (threadIdx.x < 32) {
    f4 m = (f4)0.f, v = (f4)0.f;
    for (int cc = 0; cc < CH; ++cc) {
      m += ((const f4*)Smean)[(size_t)(g * CH + cc) * 32 + threadIdx.x];
      v += ((const f4*)Svar)[(size_t)(g * CH + cc) * 32 + threadIdx.x];
    }
    m *= inv_cnt;
    v *= inv_cnt;
    f4 is;
#pragma unroll
    for (int i = 0; i < 4; ++i) is[i] = 1.0f / sqrtf(v[i] + EPSV);
    meanl[threadIdx.x] = m;
    istdl[threadIdx.x] = is;
  }
  __syncthreads();
  int csz = (len + CH - 1) / CH;
  int r0 = s + c * csz, r1 = min(r0 + csz, e);
  f4 am = ((const f4*)alpha)[lane] * meanl[lane];
  f4 is = istdl[lane];
  f4 w4 = ((const f4*)gw)[lane];
  f4 b4 = ((const f4*)gb)[lane];
  f4* out4 = (f4*)out;
  f4 mx = (f4)0.f;  // relu output >= 0, so 0 is a safe identity
  for (int r = r0 + rg; r < r1; r += 8) {
    f4 o = out4[(size_t)r * 32 + lane];
    f4 h = (o - am) * is * w4 + b4;
    h = f4_max(h, (f4)0.f);
    out4[(size_t)r * 32 + lane] = h;
    mx = f4_max(mx, h);
  }
  __shared__ f4 red[256];
  red[threadIdx.x] = mx;
  __syncthreads();
  for (int st = 4; st >= 1; st >>= 1) {
    if (rg < st) red[threadIdx.x] = f4_max(red[threadIdx.x], red[threadIdx.x + st * 32]);
    __syncthreads();
  }
  if (rg == 0) ((f4*)Pmax)[(size_t)(g * CH + c) * 32 + lane] = red[threadIdx.x];
}

// ---------------- combine partial maxes -> flat ----------------
__global__ void k_flat(const float* __restrict__ Pmax, float* __restrict__ flat) {
  int g = blockIdx.x;
  int f = threadIdx.x;  // 128 threads
  float m = 0.f;
  for (int c = 0; c < CH; ++c) m = fmaxf(m, Pmax[((size_t)g * CH + c) * 128 + f]);
  flat[g * 128 + f] = m;
}

extern "C" void kernel_launch(void* const* d_in, const int* in_sizes, int n_in,
                              void* d_out, int out_size, void* d_ws, size_t ws_size,
                              hipStream_t stream) {
  const float* inputs = (const float*)d_in[0];
  const int* eidx = (const int*)d_in[1];
  const int* batch = (const int*)d_in[2];
  const float* ew = (const float*)d_in[3];
  const float* Wg = (const float*)d_in[4];
  const float* bias = (const float*)d_in[5];
  const float* gw = (const float*)d_in[6];
  const float* gb = (const float*)d_in[7];
  const float* galpha = (const float*)d_in[8];

  int N = in_sizes[0] / 128;
  int E = in_sizes[1] / 2;
  const int* erow = eidx;       // edge_index[0] = source
  const int* ecol = eidx + E;   // edge_index[1] = target

  char* w = (char*)d_ws;
  auto alloc = [&](size_t bytes) {
    char* p = w;
    w += (bytes + 255) & ~(size_t)255;
    return p;
  };
  float* x = (float*)alloc((size_t)N * 128 * 4);
  float* deg = (float*)alloc((size_t)N * 4);
  float* dis = (float*)alloc((size_t)N * 4);
  int* ecnt = (int*)alloc((size_t)N * 4);
  int* off = (int*)alloc((size_t)(N + 1) * 4);
  int* cursor = (int*)alloc((size_t)N * 4);
  int* srow = (int*)alloc((size_t)E * 4);
  float* snorm = (float*)alloc((size_t)E * 4);
  int* gstart = (int*)alloc((size_t)(NUM_G + 1) * 4);
  float* Smean = (float*)alloc((size_t)NUM_G * CH * 128 * 4);
  float* Svar = (float*)alloc((size_t)NUM_G * CH * 128 * 4);
  float* Pmax = (float*)alloc((size_t)NUM_G * CH * 128 * 4);

  float* outh = (float*)d_out;             // h: N x 128
  float* flat = outh + (size_t)N * 128;    // flat: 64 x 128

  k_init<<<(N + 255) / 256, 256, 0, stream>>>(batch, deg, ecnt, gstart, N);
  k_deg<<<(E + 255) / 256, 256, 0, stream>>>(ecol, ew, deg, ecnt, E);
  k_scan<<<1, 1024, 0, stream>>>(ecnt, deg, off, cursor, dis, N);
  int ntiles = (N + 15) / 16;
  k_gemm<<<1024, 256, 0, stream>>>(inputs, Wg, x, N, ntiles);
  k_scatter<<<(E + 255) / 256, 256, 0, stream>>>(erow, ecol, ew, dis, cursor, srow, snorm, E);
  k_accum<<<(N + 3) / 4, 256, 0, stream>>>(x, dis, off, srow, snorm, bias, outh, N);
  k_mean_p<<<NUM_G * CH, 256, 0, stream>>>(outh, gstart, Smean);
  k_var_p<<<NUM_G * CH, 256, 0, stream>>>(outh, gstart, Smean, galpha, Svar);
  k_final<<<NUM_G * CH, 256, 0, stream>>>(outh, gstart, Smean, Svar, galpha, gw, gb, Pmax);
  k_flat<<<NUM_G, 128, 0, stream>>>(Pmax, flat);
}

// Round 3
// 376.028 us; speedup vs baseline: 2.0029x; 2.0029x over previous
//
#include <hip/hip_runtime.h>
#include <math.h>

typedef float f4 __attribute__((ext_vector_type(4)));
typedef float f2 __attribute__((ext_vector_type(2)));

#define NUM_G 64
#define CH 16          // per-graph chunks for deterministic partial reductions
#define EPSV 1e-5f

__device__ inline f4 f4_max(f4 a, f4 b) {
  f4 r;
#pragma unroll
  for (int i = 0; i < 4; ++i) r[i] = fmaxf(a[i], b[i]);
  return r;
}

// ---------------- init: deg=1 (self loop), ecnt=0, graph start offsets ----------------
__global__ void k_init(const int* __restrict__ batch, float* __restrict__ deg,
                       int* __restrict__ ecnt, int* __restrict__ gstart, int N) {
  int n = blockIdx.x * blockDim.x + threadIdx.x;
  if (n >= N) return;
  deg[n] = 1.0f;
  ecnt[n] = 0;
  int bn = batch[n];
  int bp = (n == 0) ? -1 : batch[n - 1];
  for (int g = bp + 1; g <= bn; ++g) gstart[g] = n;
  if (n == N - 1) {
    for (int g = bn + 1; g <= NUM_G; ++g) gstart[g] = N;
  }
}

// ---------------- weighted in-degree + edge count histogram ----------------
__global__ void k_deg(const int* __restrict__ col, const float* __restrict__ ew,
                      float* __restrict__ deg, int* __restrict__ ecnt, int E) {
  int e = blockIdx.x * blockDim.x + threadIdx.x;
  if (e >= E) return;
  int c = col[e];
  atomicAdd(&deg[c], ew[e]);
  atomicAdd(&ecnt[c], 1);
}

// ---------------- two-level scan, phase A: per-block totals ----------------
__global__ __launch_bounds__(256) void k_scanA(const int* __restrict__ ecnt,
                                               int* __restrict__ bsum, int N) {
  __shared__ int sb[256];
  int n = blockIdx.x * 256 + threadIdx.x;
  sb[threadIdx.x] = (n < N) ? ecnt[n] : 0;
  __syncthreads();
  for (int o = 128; o >= 1; o >>= 1) {
    if (threadIdx.x < o) sb[threadIdx.x] += sb[threadIdx.x + o];
    __syncthreads();
  }
  if (threadIdx.x == 0) bsum[blockIdx.x] = sb[0];
}

// ---------------- phase B: scan the block sums (single small block) ----------------
__global__ __launch_bounds__(1024) void k_scanB(int* __restrict__ bsum,
                                                int* __restrict__ off, int NB, int N) {
  __shared__ int sb[1024];
  int t = threadIdx.x;
  int sc = (NB + 1023) >> 10;  // entries per thread (1 for NB<=1024)
  int s = t * sc, e = min(s + sc, NB);
  int local = 0;
  for (int i = s; i < e; ++i) local += bsum[i];
  sb[t] = local;
  __syncthreads();
  for (int o = 1; o < 1024; o <<= 1) {
    int v = sb[t];
    int a = (t >= o) ? sb[t - o] : 0;
    __syncthreads();
    sb[t] = v + a;
    __syncthreads();
  }
  int running = sb[t] - local;  // exclusive base for this thread's span
  for (int i = s; i < e; ++i) {
    int v = bsum[i];
    bsum[i] = running;
    running += v;
  }
  if (t == 0) off[N] = sb[1023];  // grand total
}

// ---------------- phase C: intra-block scan + base -> off/cursor; dis = rsqrt(deg) ----------------
__global__ __launch_bounds__(256) void k_scanC(const int* __restrict__ ecnt,
                                               const int* __restrict__ bsum,
                                               const float* __restrict__ deg,
                                               int* __restrict__ off, int* __restrict__ cursor,
                                               float* __restrict__ dis, int N) {
  __shared__ int sb[256];
  int n = blockIdx.x * 256 + threadIdx.x;
  int v = (n < N) ? ecnt[n] : 0;
  sb[threadIdx.x] = v;
  __syncthreads();
  for (int o = 1; o < 256; o <<= 1) {
    int x = sb[threadIdx.x];
    int a = (threadIdx.x >= o) ? sb[threadIdx.x - o] : 0;
    __syncthreads();
    sb[threadIdx.x] = x + a;
    __syncthreads();
  }
  if (n < N) {
    int ex = bsum[blockIdx.x] + sb[threadIdx.x] - v;  // exclusive prefix
    off[n] = ex;
    cursor[n] = ex;
    float d = deg[n];
    dis[n] = (d > 0.f) ? (1.0f / sqrtf(d)) : 0.f;
  }
}

// ---------------- GEMM: x = inputs @ W  (fp32 VALU, W staged in LDS) ----------------
__global__ __launch_bounds__(256) void k_gemm(const float* __restrict__ in,
                                              const float* __restrict__ Wg,
                                              float* __restrict__ x, int N, int ntiles) {
  __shared__ float Wl[128 * 128];  // 64 KiB
  f4* Wl4 = (f4*)Wl;
  const f4* Wg4 = (const f4*)Wg;
  for (int i = threadIdx.x; i < 4096; i += 256) Wl4[i] = Wg4[i];
  __syncthreads();
  int lane = threadIdx.x & 31;  // col group: cols 4*lane..4*lane+3
  int rp = threadIdx.x >> 5;    // 0..7 -> row pair within 16-row tile
  int cg = lane * 4;
  for (int tile = blockIdx.x; tile < ntiles; tile += gridDim.x) {
    int r0 = tile * 16 + rp * 2;
    int r1 = r0 + 1;
    bool ok0 = r0 < N, ok1 = r1 < N;
    const f4* a0p = (const f4*)(in + (size_t)(ok0 ? r0 : 0) * 128);
    const f4* a1p = (const f4*)(in + (size_t)(ok1 ? r1 : 0) * 128);
    f4 acc0 = (f4)0.f, acc1 = (f4)0.f;
#pragma unroll 4
    for (int k4 = 0; k4 < 32; ++k4) {
      f4 a0 = a0p[k4];
      f4 a1 = a1p[k4];
      int kb = k4 * 4;
#pragma unroll
      for (int kk = 0; kk < 4; ++kk) {
        f4 wv = Wl4[((kb + kk) * 128 + cg) >> 2];
        acc0 += a0[kk] * wv;
        acc1 += a1[kk] * wv;
      }
    }
    if (ok0) ((f4*)(x + (size_t)r0 * 128))[lane] = acc0;
    if (ok1) ((f4*)(x + (size_t)r1 * 128))[lane] = acc1;
  }
}

// ---------------- counting-sort scatter: build CSR-by-target (srow, snorm) ----------------
__global__ void k_scatter(const int* __restrict__ row, const int* __restrict__ col,
                          const float* __restrict__ ew, const float* __restrict__ dis,
                          int* __restrict__ cursor, int* __restrict__ srow,
                          float* __restrict__ snorm, int E) {
  int e = blockIdx.x * blockDim.x + threadIdx.x;
  if (e >= E) return;
  int r = row[e], c = col[e];
  float nm = dis[r] * ew[e] * dis[c];
  int p = atomicAdd(&cursor[c], 1);
  srow[p] = r;
  snorm[p] = nm;
}

// ---------------- per-node gather-accumulate: out = sum(msg) + selfloop + bias ----------------
// one node per 64-lane wave (f2/lane = 128 feats); 4 waves (nodes) per block
__global__ __launch_bounds__(256) void k_accum(const float* __restrict__ x,
                                               const float* __restrict__ dis,
                                               const int* __restrict__ off,
                                               const int* __restrict__ srow,
                                               const float* __restrict__ snorm,
                                               const float* __restrict__ bias,
                                               float* __restrict__ out, int N) {
  int lane = threadIdx.x & 63;  // 64 lanes x float2 = 128 features
  int sub = threadIdx.x >> 6;   // 4 nodes per block
  int n = blockIdx.x * 4 + sub;
  if (n >= N) return;
  const f2* x2 = (const f2*)x;
  float dn = dis[n];
  f2 acc0 = x2[(size_t)n * 64 + lane] * (dn * dn);  // self-loop: norm = dis[n]^2
  f2 acc1 = (f2)0.f;
  int s = off[n], e = off[n + 1];
  int i = s;
  for (; i + 2 <= e; i += 2) {  // 2-deep MLP on the random row gathers
    int r0 = srow[i], r1 = srow[i + 1];
    float nm0 = snorm[i], nm1 = snorm[i + 1];
    f2 v0 = x2[(size_t)r0 * 64 + lane];
    f2 v1 = x2[(size_t)r1 * 64 + lane];
    acc0 += v0 * nm0;
    acc1 += v1 * nm1;
  }
  if (i < e) acc0 += x2[(size_t)srow[i] * 64 + lane] * snorm[i];
  acc0 += acc1 + ((const f2*)bias)[lane];
  ((f2*)out)[(size_t)n * 64 + lane] = acc0;
}

// ---------------- GraphNorm pass 1: partial sums per (graph, chunk) ----------------
__global__ __launch_bounds__(256) void k_mean_p(const float* __restrict__ out,
                                                const int* __restrict__ gstart,
                                                float* __restrict__ Smean) {
  int g = blockIdx.x / CH, c = blockIdx.x % CH;
  int s = gstart[g], e = gstart[g + 1];
  int len = e - s;
  int csz = (len + CH - 1) / CH;
  int r0 = s + c * csz, r1 = min(r0 + csz, e);
  int lane = threadIdx.x & 31, rg = threadIdx.x >> 5;
  const f4* out4 = (const f4*)out;
  f4 acc = (f4)0.f;
  for (int r = r0 + rg; r < r1; r += 8) acc += out4[(size_t)r * 32 + lane];
  __shared__ f4 red[256];
  red[threadIdx.x] = acc;
  __syncthreads();
  for (int st = 4; st >= 1; st >>= 1) {
    if (rg < st) red[threadIdx.x] += red[threadIdx.x + st * 32];
    __syncthreads();
  }
  if (rg == 0) ((f4*)Smean)[(size_t)(g * CH + c) * 32 + lane] = red[threadIdx.x];
}

// ---------------- GraphNorm pass 2: partial var sums ----------------
__global__ __launch_bounds__(256) void k_var_p(const float* __restrict__ out,
                                               const int* __restrict__ gstart,
                                               const float* __restrict__ Smean,
                                               const float* __restrict__ alpha,
                                               float* __restrict__ Svar) {
  int g = blockIdx.x / CH, c = blockIdx.x % CH;
  int s = gstart[g], e = gstart[g + 1];
  int len = e - s;
  float inv_cnt = 1.0f / (float)((len < 1) ? 1 : len);
  __shared__ f4 meanl[32];
  int lane = threadIdx.x & 31, rg = threadIdx.x >> 5;
  if (threadIdx.x < 32) {
    f4 m = (f4)0.f;
    for (int cc = 0; cc < CH; ++cc) m += ((const f4*)Smean)[(size_t)(g * CH + cc) * 32 + threadIdx.x];
    meanl[threadIdx.x] = m * inv_cnt;
  }
  __syncthreads();
  int csz = (len + CH - 1) / CH;
  int r0 = s + c * csz, r1 = min(r0 + csz, e);
  f4 am = ((const f4*)alpha)[lane] * meanl[lane];
  const f4* out4 = (const f4*)out;
  f4 acc = (f4)0.f;
  for (int r = r0 + rg; r < r1; r += 8) {
    f4 sb = out4[(size_t)r * 32 + lane] - am;
    acc += sb * sb;
  }
  __shared__ f4 red[256];
  red[threadIdx.x] = acc;
  __syncthreads();
  for (int st = 4; st >= 1; st >>= 1) {
    if (rg < st) red[threadIdx.x] += red[threadIdx.x + st * 32];
    __syncthreads();
  }
  if (rg == 0) ((f4*)Svar)[(size_t)(g * CH + c) * 32 + lane] = red[threadIdx.x];
}

// ---------------- finalize: h = relu((out-alpha*mean)*invstd*w + b); partial max ----------------
__global__ __launch_bounds__(256) void k_final(float* __restrict__ out,
                                               const int* __restrict__ gstart,
                                               const float* __restrict__ Smean,
                                               const float* __restrict__ Svar,
                                               const float* __restrict__ alpha,
                                               const float* __restrict__ gw,
                                               const float* __restrict__ gb,
                                               float* __restrict__ Pmax) {
  int g = blockIdx.x / CH, c = blockIdx.x % CH;
  int s = gstart[g], e = gstart[g + 1];
  int len = e - s;
  float inv_cnt = 1.0f / (float)((len < 1) ? 1 : len);
  __shared__ f4 meanl[32], istdl[32];
  int lane = threadIdx.x & 31, rg = threadIdx.x >> 5;
  if (threadIdx.x < 32) {
    f4 m = (f4)0.f, v = (f4)0.f;
    for (int cc = 0; cc < CH; ++cc) {
      m += ((const f4*)Smean)[(size_t)(g * CH + cc) * 32 + threadIdx.x];
      v += ((const f4*)Svar)[(size_t)(g * CH + cc) * 32 + threadIdx.x];
    }
    m *= inv_cnt;
    v *= inv_cnt;
    f4 is;
#pragma unroll
    for (int i = 0; i < 4; ++i) is[i] = 1.0f / sqrtf(v[i] + EPSV);
    meanl[threadIdx.x] = m;
    istdl[threadIdx.x] = is;
  }
  __syncthreads();
  int csz = (len + CH - 1) / CH;
  int r0 = s + c * csz, r1 = min(r0 + csz, e);
  f4 am = ((const f4*)alpha)[lane] * meanl[lane];
  f4 is = istdl[lane];
  f4 w4 = ((const f4*)gw)[lane];
  f4 b4 = ((const f4*)gb)[lane];
  f4* out4 = (f4*)out;
  f4 mx = (f4)0.f;  // relu output >= 0, so 0 is a safe identity
  for (int r = r0 + rg; r < r1; r += 8) {
    f4 o = out4[(size_t)r * 32 + lane];
    f4 h = (o - am) * is * w4 + b4;
    h = f4_max(h, (f4)0.f);
    out4[(size_t)r * 32 + lane] = h;
    mx = f4_max(mx, h);
  }
  __shared__ f4 red[256];
  red[threadIdx.x] = mx;
  __syncthreads();
  for (int st = 4; st >= 1; st >>= 1) {
    if (rg < st) red[threadIdx.x] = f4_max(red[threadIdx.x], red[threadIdx.x + st * 32]);
    __syncthreads();
  }
  if (rg == 0) ((f4*)Pmax)[(size_t)(g * CH + c) * 32 + lane] = red[threadIdx.x];
}

// ---------------- combine partial maxes -> flat ----------------
__global__ void k_flat(const float* __restrict__ Pmax, float* __restrict__ flat) {
  int g = blockIdx.x;
  int f = threadIdx.x;  // 128 threads
  float m = 0.f;
  for (int c = 0; c < CH; ++c) m = fmaxf(m, Pmax[((size_t)g * CH + c) * 128 + f]);
  flat[g * 128 + f] = m;
}

extern "C" void kernel_launch(void* const* d_in, const int* in_sizes, int n_in,
                              void* d_out, int out_size, void* d_ws, size_t ws_size,
                              hipStream_t stream) {
  const float* inputs = (const float*)d_in[0];
  const int* eidx = (const int*)d_in[1];
  const int* batch = (const int*)d_in[2];
  const float* ew = (const float*)d_in[3];
  const float* Wg = (const float*)d_in[4];
  const float* bias = (const float*)d_in[5];
  const float* gw = (const float*)d_in[6];
  const float* gb = (const float*)d_in[7];
  const float* galpha = (const float*)d_in[8];

  int N = in_sizes[0] / 128;
  int E = in_sizes[1] / 2;
  const int* erow = eidx;       // edge_index[0] = source
  const int* ecol = eidx + E;   // edge_index[1] = target

  char* w = (char*)d_ws;
  auto alloc = [&](size_t bytes) {
    char* p = w;
    w += (bytes + 255) & ~(size_t)255;
    return p;
  };
  float* x = (float*)alloc((size_t)N * 128 * 4);
  float* deg = (float*)alloc((size_t)N * 4);
  float* dis = (float*)alloc((size_t)N * 4);
  int* ecnt = (int*)alloc((size_t)N * 4);
  int* off = (int*)alloc((size_t)(N + 1) * 4);
  int* cursor = (int*)alloc((size_t)N * 4);
  int* srow = (int*)alloc((size_t)E * 4);
  float* snorm = (float*)alloc((size_t)E * 4);
  int* gstart = (int*)alloc((size_t)(NUM_G + 1) * 4);
  float* Smean = (float*)alloc((size_t)NUM_G * CH * 128 * 4);
  float* Svar = (float*)alloc((size_t)NUM_G * CH * 128 * 4);
  float* Pmax = (float*)alloc((size_t)NUM_G * CH * 128 * 4);
  int NB = (N + 255) / 256;
  int* bsum = (int*)alloc((size_t)NB * 4);

  float* outh = (float*)d_out;             // h: N x 128
  float* flat = outh + (size_t)N * 128;    // flat: 64 x 128

  k_init<<<(N + 255) / 256, 256, 0, stream>>>(batch, deg, ecnt, gstart, N);
  k_deg<<<(E + 255) / 256, 256, 0, stream>>>(ecol, ew, deg, ecnt, E);
  k_scanA<<<NB, 256, 0, stream>>>(ecnt, bsum, N);
  k_scanB<<<1, 1024, 0, stream>>>(bsum, off, NB, N);
  k_scanC<<<NB, 256, 0, stream>>>(ecnt, bsum, deg, off, cursor, dis, N);
  int ntiles = (N + 15) / 16;
  k_gemm<<<1024, 256, 0, stream>>>(inputs, Wg, x, N, ntiles);
  k_scatter<<<(E + 255) / 256, 256, 0, stream>>>(erow, ecol, ew, dis, cursor, srow, snorm, E);
  k_accum<<<(N + 3) / 4, 256, 0, stream>>>(x, dis, off, srow, snorm, bias, outh, N);
  k_mean_p<<<NUM_G * CH, 256, 0, stream>>>(outh, gstart, Smean);
  k_var_p<<<NUM_G * CH, 256, 0, stream>>>(outh, gstart, Smean, galpha, Svar);
  k_final<<<NUM_G * CH, 256, 0, stream>>>(outh, gstart, Smean, Svar, galpha, gw, gb, Pmax);
  k_flat<<<NUM_G, 128, 0, stream>>>(Pmax, flat);
}

// Round 8
// 366.967 us; speedup vs baseline: 2.0523x; 1.0247x over previous
//
#include <hip/hip_runtime.h>
#include <math.h>

typedef float f4 __attribute__((ext_vector_type(4)));
typedef float f2 __attribute__((ext_vector_type(2)));

#define NUM_G 64
#define CH 16          // per-graph chunks for deterministic partial reductions
#define EPSV 1e-5f

__device__ inline f4 f4_max(f4 a, f4 b) {
  f4 r;
#pragma unroll
  for (int i = 0; i < 4; ++i) r[i] = fmaxf(a[i], b[i]);
  return r;
}

// ---------------- init: deg=1 (self loop), ecnt=0, graph start offsets ----------------
__global__ void k_init(const int* __restrict__ batch, float* __restrict__ deg,
                       int* __restrict__ ecnt, int* __restrict__ gstart, int N) {
  int n = blockIdx.x * blockDim.x + threadIdx.x;
  if (n >= N) return;
  deg[n] = 1.0f;
  ecnt[n] = 0;
  int bn = batch[n];
  int bp = (n == 0) ? -1 : batch[n - 1];
  for (int g = bp + 1; g <= bn; ++g) gstart[g] = n;
  if (n == N - 1) {
    for (int g = bn + 1; g <= NUM_G; ++g) gstart[g] = N;
  }
}

// ---------------- weighted in-degree + edge count histogram ----------------
__global__ void k_deg(const int* __restrict__ col, const float* __restrict__ ew,
                      float* __restrict__ deg, int* __restrict__ ecnt, int E) {
  int e = blockIdx.x * blockDim.x + threadIdx.x;
  if (e >= E) return;
  int c = col[e];
  atomicAdd(&deg[c], ew[e]);
  atomicAdd(&ecnt[c], 1);
}

// ---------------- two-level scan, phase A: per-block totals ----------------
__global__ __launch_bounds__(256) void k_scanA(const int* __restrict__ ecnt,
                                               int* __restrict__ bsum, int N) {
  __shared__ int sb[256];
  int n = blockIdx.x * 256 + threadIdx.x;
  sb[threadIdx.x] = (n < N) ? ecnt[n] : 0;
  __syncthreads();
  for (int o = 128; o >= 1; o >>= 1) {
    if (threadIdx.x < o) sb[threadIdx.x] += sb[threadIdx.x + o];
    __syncthreads();
  }
  if (threadIdx.x == 0) bsum[blockIdx.x] = sb[0];
}

// ---------------- phase B: scan the block sums (single small block) ----------------
__global__ __launch_bounds__(1024) void k_scanB(int* __restrict__ bsum,
                                                int* __restrict__ off, int NB, int N) {
  __shared__ int sb[1024];
  int t = threadIdx.x;
  int sc = (NB + 1023) >> 10;  // entries per thread (1 for NB<=1024)
  int s = t * sc, e = min(s + sc, NB);
  int local = 0;
  for (int i = s; i < e; ++i) local += bsum[i];
  sb[t] = local;
  __syncthreads();
  for (int o = 1; o < 1024; o <<= 1) {
    int v = sb[t];
    int a = (t >= o) ? sb[t - o] : 0;
    __syncthreads();
    sb[t] = v + a;
    __syncthreads();
  }
  int running = sb[t] - local;  // exclusive base for this thread's span
  for (int i = s; i < e; ++i) {
    int v = bsum[i];
    bsum[i] = running;
    running += v;
  }
  if (t == 0) off[N] = sb[1023];  // grand total
}

// ---------------- phase C: intra-block scan + base -> off/cursor; dis = rsqrt(deg) ----------------
__global__ __launch_bounds__(256) void k_scanC(const int* __restrict__ ecnt,
                                               const int* __restrict__ bsum,
                                               const float* __restrict__ deg,
                                               int* __restrict__ off, int* __restrict__ cursor,
                                               float* __restrict__ dis, int N) {
  __shared__ int sb[256];
  int n = blockIdx.x * 256 + threadIdx.x;
  int v = (n < N) ? ecnt[n] : 0;
  sb[threadIdx.x] = v;
  __syncthreads();
  for (int o = 1; o < 256; o <<= 1) {
    int x = sb[threadIdx.x];
    int a = (threadIdx.x >= o) ? sb[threadIdx.x - o] : 0;
    __syncthreads();
    sb[threadIdx.x] = x + a;
    __syncthreads();
  }
  if (n < N) {
    int ex = bsum[blockIdx.x] + sb[threadIdx.x] - v;  // exclusive prefix
    off[n] = ex;
    cursor[n] = ex;
    float d = deg[n];
    dis[n] = (d > 0.f) ? (1.0f / sqrtf(d)) : 0.f;
  }
}

// ---------------- GEMM: x = inputs @ W  (fp32 VALU, W in LDS, 4x4 register block) ----------------
// 512 threads: lane=tid&31 -> 4 cols, rg=tid>>5 (0..15) -> 4 rows; 64 rows/block-tile
__global__ __launch_bounds__(512) void k_gemm(const float* __restrict__ in,
                                              const float* __restrict__ Wg,
                                              float* __restrict__ x, int N, int ntiles) {
  __shared__ float Wl[128 * 128];  // 64 KiB
  f4* Wl4 = (f4*)Wl;
  const f4* Wg4 = (const f4*)Wg;
  for (int i = threadIdx.x; i < 4096; i += 512) Wl4[i] = Wg4[i];
  __syncthreads();
  int lane = threadIdx.x & 31;  // cols 4*lane..4*lane+3
  int rg = threadIdx.x >> 5;    // row group
  for (int tile = blockIdx.x; tile < ntiles; tile += gridDim.x) {
    int r0 = tile * 64 + rg * 4;
    bool ok0 = r0 + 0 < N, ok1 = r0 + 1 < N, ok2 = r0 + 2 < N, ok3 = r0 + 3 < N;
    const f4* a0 = (const f4*)(in + (size_t)(ok0 ? r0 + 0 : 0) * 128);
    const f4* a1 = (const f4*)(in + (size_t)(ok1 ? r0 + 1 : 0) * 128);
    const f4* a2 = (const f4*)(in + (size_t)(ok2 ? r0 + 2 : 0) * 128);
    const f4* a3 = (const f4*)(in + (size_t)(ok3 ? r0 + 3 : 0) * 128);
    f4 acc0 = (f4)0.f, acc1 = (f4)0.f, acc2 = (f4)0.f, acc3 = (f4)0.f;
#pragma unroll 4
    for (int k4 = 0; k4 < 32; ++k4) {
      f4 a0v = a0[k4], a1v = a1[k4], a2v = a2[k4], a3v = a3[k4];
#pragma unroll
      for (int kk = 0; kk < 4; ++kk) {
        f4 wv = Wl4[(k4 * 4 + kk) * 32 + lane];
        acc0 += a0v[kk] * wv;
        acc1 += a1v[kk] * wv;
        acc2 += a2v[kk] * wv;
        acc3 += a3v[kk] * wv;
      }
    }
    if (ok0) ((f4*)(x + (size_t)(r0 + 0) * 128))[lane] = acc0;
    if (ok1) ((f4*)(x + (size_t)(r0 + 1) * 128))[lane] = acc1;
    if (ok2) ((f4*)(x + (size_t)(r0 + 2) * 128))[lane] = acc2;
    if (ok3) ((f4*)(x + (size_t)(r0 + 3) * 128))[lane] = acc3;
  }
}

// ---------------- counting-sort scatter: build CSR-by-target (srow, snorm) ----------------
__global__ void k_scatter(const int* __restrict__ row, const int* __restrict__ col,
                          const float* __restrict__ ew, const float* __restrict__ dis,
                          int* __restrict__ cursor, int* __restrict__ srow,
                          float* __restrict__ snorm, int E) {
  int e = blockIdx.x * blockDim.x + threadIdx.x;
  if (e >= E) return;
  int r = row[e], c = col[e];
  float nm = dis[r] * ew[e] * dis[c];
  int p = atomicAdd(&cursor[c], 1);
  srow[p] = r;
  snorm[p] = nm;
}

// ---------------- per-node gather-accumulate: out = sum(msg) + selfloop + bias ----------------
// one node per 64-lane wave (f2/lane = 128 feats); 4 waves (nodes) per block
__global__ __launch_bounds__(256) void k_accum(const float* __restrict__ x,
                                               const float* __restrict__ dis,
                                               const int* __restrict__ off,
                                               const int* __restrict__ srow,
                                               const float* __restrict__ snorm,
                                               const float* __restrict__ bias,
                                               float* __restrict__ out, int N) {
  int lane = threadIdx.x & 63;  // 64 lanes x float2 = 128 features
  int sub = threadIdx.x >> 6;   // 4 nodes per block
  int n = blockIdx.x * 4 + sub;
  if (n >= N) return;
  const f2* x2 = (const f2*)x;
  float dn = dis[n];
  f2 acc0 = x2[(size_t)n * 64 + lane] * (dn * dn);  // self-loop: norm = dis[n]^2
  f2 acc1 = (f2)0.f, acc2 = (f2)0.f, acc3 = (f2)0.f;
  int s = off[n], e = off[n + 1];
  int i = s;
  for (; i + 4 <= e; i += 4) {  // 4-deep MLP on the random row gathers
    int r0 = srow[i], r1 = srow[i + 1], r2 = srow[i + 2], r3 = srow[i + 3];
    float n0 = snorm[i], n1 = snorm[i + 1], n2 = snorm[i + 2], n3 = snorm[i + 3];
    acc0 += x2[(size_t)r0 * 64 + lane] * n0;
    acc1 += x2[(size_t)r1 * 64 + lane] * n1;
    acc2 += x2[(size_t)r2 * 64 + lane] * n2;
    acc3 += x2[(size_t)r3 * 64 + lane] * n3;
  }
  for (; i < e; ++i) acc0 += x2[(size_t)srow[i] * 64 + lane] * snorm[i];
  acc0 += (acc1 + acc2) + (acc3 + ((const f2*)bias)[lane]);
  ((f2*)out)[(size_t)n * 64 + lane] = acc0;
}

// ---------------- GraphNorm fused stats: partial sum AND sum-of-squares per (graph, chunk) ----------------
__global__ __launch_bounds__(256) void k_stats(const float* __restrict__ out,
                                               const int* __restrict__ gstart,
                                               float* __restrict__ Ssum,
                                               float* __restrict__ Ssq) {
  int g = blockIdx.x / CH, c = blockIdx.x % CH;
  int s = gstart[g], e = gstart[g + 1];
  int len = e - s;
  int csz = (len + CH - 1) / CH;
  int r0 = s + c * csz, r1 = min(r0 + csz, e);
  int lane = threadIdx.x & 31, rg = threadIdx.x >> 5;
  const f4* out4 = (const f4*)out;
  f4 acc = (f4)0.f, accq = (f4)0.f;
  for (int r = r0 + rg; r < r1; r += 8) {
    f4 v = out4[(size_t)r * 32 + lane];
    acc += v;
    accq += v * v;
  }
  __shared__ f4 red[256], redq[256];
  red[threadIdx.x] = acc;
  redq[threadIdx.x] = accq;
  __syncthreads();
  for (int st = 4; st >= 1; st >>= 1) {
    if (rg < st) {
      red[threadIdx.x] += red[threadIdx.x + st * 32];
      redq[threadIdx.x] += redq[threadIdx.x + st * 32];
    }
    __syncthreads();
  }
  if (rg == 0) {
    ((f4*)Ssum)[(size_t)(g * CH + c) * 32 + lane] = red[threadIdx.x];
    ((f4*)Ssq)[(size_t)(g * CH + c) * 32 + lane] = redq[threadIdx.x];
  }
}

// ---------------- finalize: h = relu((out-alpha*mean)*invstd*w + b); partial max ----------------
// var = E[(out-am)^2] = E[out^2] - 2*am*E[out] + am^2, am = alpha*mean
__global__ __launch_bounds__(256) void k_final(float* __restrict__ out,
                                               const int* __restrict__ gstart,
                                               const float* __restrict__ Ssum,
                                               const float* __restrict__ Ssq,
                                               const float* __restrict__ alpha,
                                               const float* __restrict__ gw,
                                               const float* __restrict__ gb,
                                               float* __restrict__ Pmax) {
  int g = blockIdx.x / CH, c = blockIdx.x % CH;
  int s = gstart[g], e = gstart[g + 1];
  int len = e - s;
  float inv_cnt = 1.0f / (float)((len < 1) ? 1 : len);
  __shared__ f4 aml[32], istdl[32];
  int lane = threadIdx.x & 31, rg = threadIdx.x >> 5;
  if (threadIdx.x < 32) {
    f4 m = (f4)0.f, q = (f4)0.f;
    for (int cc = 0; cc < CH; ++cc) {
      m += ((const f4*)Ssum)[(size_t)(g * CH + cc) * 32 + threadIdx.x];
      q += ((const f4*)Ssq)[(size_t)(g * CH + cc) * 32 + threadIdx.x];
    }
    m *= inv_cnt;                                 // E[out]
    q *= inv_cnt;                                 // E[out^2]
    f4 al = ((const f4*)alpha)[threadIdx.x];
    f4 am = al * m;
    f4 var = q - 2.0f * am * m + am * am;         // E[(out-am)^2]
    f4 is;
#pragma unroll
    for (int i = 0; i < 4; ++i) is[i] = 1.0f / sqrtf(var[i] + EPSV);
    aml[threadIdx.x] = am;
    istdl[threadIdx.x] = is;
  }
  __syncthreads();
  int csz = (len + CH - 1) / CH;
  int r0 = s + c * csz, r1 = min(r0 + csz, e);
  f4 am = aml[lane];
  f4 is = istdl[lane];
  f4 w4 = ((const f4*)gw)[lane];
  f4 b4 = ((const f4*)gb)[lane];
  f4* out4 = (f4*)out;
  f4 mx = (f4)0.f;  // relu output >= 0, so 0 is a safe identity
  for (int r = r0 + rg; r < r1; r += 8) {
    f4 o = out4[(size_t)r * 32 + lane];
    f4 h = (o - am) * is * w4 + b4;
    h = f4_max(h, (f4)0.f);
    out4[(size_t)r * 32 + lane] = h;
    mx = f4_max(mx, h);
  }
  __shared__ f4 red[256];
  red[threadIdx.x] = mx;
  __syncthreads();
  for (int st = 4; st >= 1; st >>= 1) {
    if (rg < st) red[threadIdx.x] = f4_max(red[threadIdx.x], red[threadIdx.x + st * 32]);
    __syncthreads();
  }
  if (rg == 0) ((f4*)Pmax)[(size_t)(g * CH + c) * 32 + lane] = red[threadIdx.x];
}

// ---------------- combine partial maxes -> flat ----------------
__global__ void k_flat(const float* __restrict__ Pmax, float* __restrict__ flat) {
  int g = blockIdx.x;
  int f = threadIdx.x;  // 128 threads
  float m = 0.f;
  for (int c = 0; c < CH; ++c) m = fmaxf(m, Pmax[((size_t)g * CH + c) * 128 + f]);
  flat[g * 128 + f] = m;
}

extern "C" void kernel_launch(void* const* d_in, const int* in_sizes, int n_in,
                              void* d_out, int out_size, void* d_ws, size_t ws_size,
                              hipStream_t stream) {
  const float* inputs = (const float*)d_in[0];
  const int* eidx = (const int*)d_in[1];
  const int* batch = (const int*)d_in[2];
  const float* ew = (const float*)d_in[3];
  const float* Wg = (const float*)d_in[4];
  const float* bias = (const float*)d_in[5];
  const float* gw = (const float*)d_in[6];
  const float* gb = (const float*)d_in[7];
  const float* galpha = (const float*)d_in[8];

  int N = in_sizes[0] / 128;
  int E = in_sizes[1] / 2;
  const int* erow = eidx;       // edge_index[0] = source
  const int* ecol = eidx + E;   // edge_index[1] = target

  char* w = (char*)d_ws;
  auto alloc = [&](size_t bytes) {
    char* p = w;
    w += (bytes + 255) & ~(size_t)255;
    return p;
  };
  float* x = (float*)alloc((size_t)N * 128 * 4);
  float* deg = (float*)alloc((size_t)N * 4);
  float* dis = (float*)alloc((size_t)N * 4);
  int* ecnt = (int*)alloc((size_t)N * 4);
  int* off = (int*)alloc((size_t)(N + 1) * 4);
  int* cursor = (int*)alloc((size_t)N * 4);
  int* srow = (int*)alloc((size_t)E * 4);
  float* snorm = (float*)alloc((size_t)E * 4);
  int* gstart = (int*)alloc((size_t)(NUM_G + 1) * 4);
  float* Ssum = (float*)alloc((size_t)NUM_G * CH * 128 * 4);
  float* Ssq = (float*)alloc((size_t)NUM_G * CH * 128 * 4);
  float* Pmax = (float*)alloc((size_t)NUM_G * CH * 128 * 4);
  int NB = (N + 255) / 256;
  int* bsum = (int*)alloc((size_t)NB * 4);

  float* outh = (float*)d_out;             // h: N x 128
  float* flat = outh + (size_t)N * 128;    // flat: 64 x 128

  k_init<<<(N + 255) / 256, 256, 0, stream>>>(batch, deg, ecnt, gstart, N);
  k_deg<<<(E + 255) / 256, 256, 0, stream>>>(ecol, ew, deg, ecnt, E);
  k_scanA<<<NB, 256, 0, stream>>>(ecnt, bsum, N);
  k_scanB<<<1, 1024, 0, stream>>>(bsum, off, NB, N);
  k_scanC<<<NB, 256, 0, stream>>>(ecnt, bsum, deg, off, cursor, dis, N);
  int ntiles = (N + 63) / 64;
  k_gemm<<<ntiles, 512, 0, stream>>>(inputs, Wg, x, N, ntiles);
  k_scatter<<<(E + 255) / 256, 256, 0, stream>>>(erow, ecol, ew, dis, cursor, srow, snorm, E);
  k_accum<<<(N + 3) / 4, 256, 0, stream>>>(x, dis, off, srow, snorm, bias, outh, N);
  k_stats<<<NUM_G * CH, 256, 0, stream>>>(outh, gstart, Ssum, Ssq);
  k_final<<<NUM_G * CH, 256, 0, stream>>>(outh, gstart, Ssum, Ssq, galpha, gw, gb, Pmax);
  k_flat<<<NUM_G, 128, 0, stream>>>(Pmax, flat);
}

// Round 10
// 339.380 us; speedup vs baseline: 2.2192x; 1.0813x over previous
//
#include <hip/hip_runtime.h>
#include <math.h>

typedef float f4 __attribute__((ext_vector_type(4)));
typedef float f2 __attribute__((ext_vector_type(2)));

#define NUM_G 64
#define CH 16          // per-graph chunks for deterministic partial reductions
#define EPSV 1e-5f

__device__ inline f4 f4_max(f4 a, f4 b) {
  f4 r;
#pragma unroll
  for (int i = 0; i < 4; ++i) r[i] = fmaxf(a[i], b[i]);
  return r;
}

// ---------------- init: deg=1 (self loop), ecnt=0, graph start offsets ----------------
__global__ void k_init(const int* __restrict__ batch, float* __restrict__ deg,
                       int* __restrict__ ecnt, int* __restrict__ gstart, int N) {
  int n = blockIdx.x * blockDim.x + threadIdx.x;
  if (n >= N) return;
  deg[n] = 1.0f;
  ecnt[n] = 0;
  int bn = batch[n];
  int bp = (n == 0) ? -1 : batch[n - 1];
  for (int g = bp + 1; g <= bn; ++g) gstart[g] = n;
  if (n == N - 1) {
    for (int g = bn + 1; g <= NUM_G; ++g) gstart[g] = N;
  }
}

// ---------------- weighted in-degree + edge count histogram ----------------
__global__ void k_deg(const int* __restrict__ col, const float* __restrict__ ew,
                      float* __restrict__ deg, int* __restrict__ ecnt, int E) {
  int e = blockIdx.x * blockDim.x + threadIdx.x;
  if (e >= E) return;
  int c = col[e];
  atomicAdd(&deg[c], ew[e]);
  atomicAdd(&ecnt[c], 1);
}

// ---------------- two-level scan, phase A: per-block totals ----------------
__global__ __launch_bounds__(256) void k_scanA(const int* __restrict__ ecnt,
                                               int* __restrict__ bsum, int N) {
  __shared__ int sb[256];
  int n = blockIdx.x * 256 + threadIdx.x;
  sb[threadIdx.x] = (n < N) ? ecnt[n] : 0;
  __syncthreads();
  for (int o = 128; o >= 1; o >>= 1) {
    if (threadIdx.x < o) sb[threadIdx.x] += sb[threadIdx.x + o];
    __syncthreads();
  }
  if (threadIdx.x == 0) bsum[blockIdx.x] = sb[0];
}

// ---------------- phase B: scan the block sums (single small block) ----------------
__global__ __launch_bounds__(1024) void k_scanB(int* __restrict__ bsum,
                                                int* __restrict__ off, int NB, int N) {
  __shared__ int sb[1024];
  int t = threadIdx.x;
  int sc = (NB + 1023) >> 10;  // entries per thread (1 for NB<=1024)
  int s = t * sc, e = min(s + sc, NB);
  int local = 0;
  for (int i = s; i < e; ++i) local += bsum[i];
  sb[t] = local;
  __syncthreads();
  for (int o = 1; o < 1024; o <<= 1) {
    int v = sb[t];
    int a = (t >= o) ? sb[t - o] : 0;
    __syncthreads();
    sb[t] = v + a;
    __syncthreads();
  }
  int running = sb[t] - local;  // exclusive base for this thread's span
  for (int i = s; i < e; ++i) {
    int v = bsum[i];
    bsum[i] = running;
    running += v;
  }
  if (t == 0) off[N] = sb[1023];  // grand total
}

// ---------------- phase C: intra-block scan + base -> off/cursor; dis = rsqrt(deg) ----------------
__global__ __launch_bounds__(256) void k_scanC(const int* __restrict__ ecnt,
                                               const int* __restrict__ bsum,
                                               const float* __restrict__ deg,
                                               int* __restrict__ off, int* __restrict__ cursor,
                                               float* __restrict__ dis, int N) {
  __shared__ int sb[256];
  int n = blockIdx.x * 256 + threadIdx.x;
  int v = (n < N) ? ecnt[n] : 0;
  sb[threadIdx.x] = v;
  __syncthreads();
  for (int o = 1; o < 256; o <<= 1) {
    int x = sb[threadIdx.x];
    int a = (threadIdx.x >= o) ? sb[threadIdx.x - o] : 0;
    __syncthreads();
    sb[threadIdx.x] = x + a;
    __syncthreads();
  }
  if (n < N) {
    int ex = bsum[blockIdx.x] + sb[threadIdx.x] - v;  // exclusive prefix
    off[n] = ex;
    cursor[n] = ex;
    float d = deg[n];
    dis[n] = (d > 0.f) ? (1.0f / sqrtf(d)) : 0.f;
  }
}

// ---------------- GEMM: x = inputs @ W, both tiles LDS-staged (coalesced A!) ----------------
// BM=64, BK=32, BN=128. 512 threads: lane=tid&31 -> 4 cols, rg=tid>>5 (0..15) -> 4 rows.
// Previous version loaded A with lane-uniform 16B global loads -> ~32B unique/wave/instr
// -> transaction-bound at ~950 GB/s. Staging A coalesced fixes the transaction efficiency.
__global__ __launch_bounds__(512) void k_gemm(const float* __restrict__ in,
                                              const float* __restrict__ Wg,
                                              float* __restrict__ x, int N) {
  __shared__ float As[64][32];   // 8 KiB
  __shared__ float Ws[32][128];  // 16 KiB
  int tid = threadIdx.x;
  int lane = tid & 31;   // cols 4*lane..4*lane+3
  int rg = tid >> 5;     // rows rg*4..rg*4+3
  int brow = blockIdx.x * 64;
  int ar = tid >> 3;         // 0..63: A stage row
  int aseg = (tid & 7) * 4;  // float offset within 32-float chunk
  const f4* wsrc0 = (const f4*)Wg;
  f4 acc0 = (f4)0.f, acc1 = (f4)0.f, acc2 = (f4)0.f, acc3 = (f4)0.f;
  for (int kc = 0; kc < 4; ++kc) {  // K chunks of 32, ascending (same summation order)
    // stage A: 64 rows x 32 floats; 8 consecutive threads cover one row chunk (coalesced 128B)
    int gr = brow + ar;
    f4 av = (f4)0.f;
    if (gr < N) av = *(const f4*)(in + (size_t)gr * 128 + kc * 32 + aseg);
    *(f4*)&As[ar][aseg] = av;
    // stage W chunk: 32 rows x 128 cols = 1024 f4, fully linear copy
    const f4* wsrc = wsrc0 + (size_t)kc * 32 * 32;  // kc*32 rows, 32 f4 per row
    ((f4*)Ws)[tid] = wsrc[tid];
    ((f4*)Ws)[tid + 512] = wsrc[tid + 512];
    __syncthreads();
#pragma unroll
    for (int k4 = 0; k4 < 8; ++k4) {
      f4 a0 = *(const f4*)&As[rg * 4 + 0][k4 * 4];
      f4 a1 = *(const f4*)&As[rg * 4 + 1][k4 * 4];
      f4 a2 = *(const f4*)&As[rg * 4 + 2][k4 * 4];
      f4 a3 = *(const f4*)&As[rg * 4 + 3][k4 * 4];
#pragma unroll
      for (int kk = 0; kk < 4; ++kk) {
        f4 wv = *(const f4*)&Ws[k4 * 4 + kk][lane * 4];
        acc0 += a0[kk] * wv;
        acc1 += a1[kk] * wv;
        acc2 += a2[kk] * wv;
        acc3 += a3[kk] * wv;
      }
    }
    __syncthreads();
  }
  int r0 = brow + rg * 4;
  if (r0 + 0 < N) ((f4*)(x + (size_t)(r0 + 0) * 128))[lane] = acc0;
  if (r0 + 1 < N) ((f4*)(x + (size_t)(r0 + 1) * 128))[lane] = acc1;
  if (r0 + 2 < N) ((f4*)(x + (size_t)(r0 + 2) * 128))[lane] = acc2;
  if (r0 + 3 < N) ((f4*)(x + (size_t)(r0 + 3) * 128))[lane] = acc3;
}

// ---------------- counting-sort scatter: build CSR-by-target (srow, snorm) ----------------
__global__ void k_scatter(const int* __restrict__ row, const int* __restrict__ col,
                          const float* __restrict__ ew, const float* __restrict__ dis,
                          int* __restrict__ cursor, int* __restrict__ srow,
                          float* __restrict__ snorm, int E) {
  int e = blockIdx.x * blockDim.x + threadIdx.x;
  if (e >= E) return;
  int r = row[e], c = col[e];
  float nm = dis[r] * ew[e] * dis[c];
  int p = atomicAdd(&cursor[c], 1);
  srow[p] = r;
  snorm[p] = nm;
}

// ---------------- per-node gather-accumulate: out = sum(msg) + selfloop + bias ----------------
// one node per 64-lane wave (f2/lane = 128 feats); 4 waves (nodes) per block
__global__ __launch_bounds__(256) void k_accum(const float* __restrict__ x,
                                               const float* __restrict__ dis,
                                               const int* __restrict__ off,
                                               const int* __restrict__ srow,
                                               const float* __restrict__ snorm,
                                               const float* __restrict__ bias,
                                               float* __restrict__ out, int N) {
  int lane = threadIdx.x & 63;  // 64 lanes x float2 = 128 features
  int sub = threadIdx.x >> 6;   // 4 nodes per block
  int n = blockIdx.x * 4 + sub;
  if (n >= N) return;
  const f2* x2 = (const f2*)x;
  float dn = dis[n];
  f2 acc0 = x2[(size_t)n * 64 + lane] * (dn * dn);  // self-loop: norm = dis[n]^2
  f2 acc1 = (f2)0.f, acc2 = (f2)0.f, acc3 = (f2)0.f;
  int s = off[n], e = off[n + 1];
  int i = s;
  for (; i + 4 <= e; i += 4) {  // 4-deep MLP on the random row gathers
    int r0 = srow[i], r1 = srow[i + 1], r2 = srow[i + 2], r3 = srow[i + 3];
    float n0 = snorm[i], n1 = snorm[i + 1], n2 = snorm[i + 2], n3 = snorm[i + 3];
    acc0 += x2[(size_t)r0 * 64 + lane] * n0;
    acc1 += x2[(size_t)r1 * 64 + lane] * n1;
    acc2 += x2[(size_t)r2 * 64 + lane] * n2;
    acc3 += x2[(size_t)r3 * 64 + lane] * n3;
  }
  for (; i < e; ++i) acc0 += x2[(size_t)srow[i] * 64 + lane] * snorm[i];
  acc0 += (acc1 + acc2) + (acc3 + ((const f2*)bias)[lane]);
  ((f2*)out)[(size_t)n * 64 + lane] = acc0;
}

// ---------------- GraphNorm fused stats: partial sum AND sum-of-squares per (graph, chunk) ----------------
__global__ __launch_bounds__(256) void k_stats(const float* __restrict__ out,
                                               const int* __restrict__ gstart,
                                               float* __restrict__ Ssum,
                                               float* __restrict__ Ssq) {
  int g = blockIdx.x / CH, c = blockIdx.x % CH;
  int s = gstart[g], e = gstart[g + 1];
  int len = e - s;
  int csz = (len + CH - 1) / CH;
  int r0 = s + c * csz, r1 = min(r0 + csz, e);
  int lane = threadIdx.x & 31, rg = threadIdx.x >> 5;
  const f4* out4 = (const f4*)out;
  f4 acc = (f4)0.f, accq = (f4)0.f;
  for (int r = r0 + rg; r < r1; r += 8) {
    f4 v = out4[(size_t)r * 32 + lane];
    acc += v;
    accq += v * v;
  }
  __shared__ f4 red[256], redq[256];
  red[threadIdx.x] = acc;
  redq[threadIdx.x] = accq;
  __syncthreads();
  for (int st = 4; st >= 1; st >>= 1) {
    if (rg < st) {
      red[threadIdx.x] += red[threadIdx.x + st * 32];
      redq[threadIdx.x] += redq[threadIdx.x + st * 32];
    }
    __syncthreads();
  }
  if (rg == 0) {
    ((f4*)Ssum)[(size_t)(g * CH + c) * 32 + lane] = red[threadIdx.x];
    ((f4*)Ssq)[(size_t)(g * CH + c) * 32 + lane] = redq[threadIdx.x];
  }
}

// ---------------- finalize: h = relu((out-alpha*mean)*invstd*w + b); partial max ----------------
// var = E[(out-am)^2] = E[out^2] - 2*am*E[out] + am^2, am = alpha*mean
__global__ __launch_bounds__(256) void k_final(float* __restrict__ out,
                                               const int* __restrict__ gstart,
                                               const float* __restrict__ Ssum,
                                               const float* __restrict__ Ssq,
                                               const float* __restrict__ alpha,
                                               const float* __restrict__ gw,
                                               const float* __restrict__ gb,
                                               float* __restrict__ Pmax) {
  int g = blockIdx.x / CH, c = blockIdx.x % CH;
  int s = gstart[g], e = gstart[g + 1];
  int len = e - s;
  float inv_cnt = 1.0f / (float)((len < 1) ? 1 : len);
  __shared__ f4 aml[32], istdl[32];
  int lane = threadIdx.x & 31, rg = threadIdx.x >> 5;
  if (threadIdx.x < 32) {
    f4 m = (f4)0.f, q = (f4)0.f;
    for (int cc = 0; cc < CH; ++cc) {
      m += ((const f4*)Ssum)[(size_t)(g * CH + cc) * 32 + threadIdx.x];
      q += ((const f4*)Ssq)[(size_t)(g * CH + cc) * 32 + threadIdx.x];
    }
    m *= inv_cnt;                                 // E[out]
    q *= inv_cnt;                                 // E[out^2]
    f4 al = ((const f4*)alpha)[threadIdx.x];
    f4 am = al * m;
    f4 var = q - 2.0f * am * m + am * am;         // E[(out-am)^2]
    f4 is;
#pragma unroll
    for (int i = 0; i < 4; ++i) is[i] = 1.0f / sqrtf(var[i] + EPSV);
    aml[threadIdx.x] = am;
    istdl[threadIdx.x] = is;
  }
  __syncthreads();
  int csz = (len + CH - 1) / CH;
  int r0 = s + c * csz, r1 = min(r0 + csz, e);
  f4 am = aml[lane];
  f4 is = istdl[lane];
  f4 w4 = ((const f4*)gw)[lane];
  f4 b4 = ((const f4*)gb)[lane];
  f4* out4 = (f4*)out;
  f4 mx = (f4)0.f;  // relu output >= 0, so 0 is a safe identity
  for (int r = r0 + rg; r < r1; r += 8) {
    f4 o = out4[(size_t)r * 32 + lane];
    f4 h = (o - am) * is * w4 + b4;
    h = f4_max(h, (f4)0.f);
    out4[(size_t)r * 32 + lane] = h;
    mx = f4_max(mx, h);
  }
  __shared__ f4 red[256];
  red[threadIdx.x] = mx;
  __syncthreads();
  for (int st = 4; st >= 1; st >>= 1) {
    if (rg < st) red[threadIdx.x] = f4_max(red[threadIdx.x], red[threadIdx.x + st * 32]);
    __syncthreads();
  }
  if (rg == 0) ((f4*)Pmax)[(size_t)(g * CH + c) * 32 + lane] = red[threadIdx.x];
}

// ---------------- combine partial maxes -> flat ----------------
__global__ void k_flat(const float* __restrict__ Pmax, float* __restrict__ flat) {
  int g = blockIdx.x;
  int f = threadIdx.x;  // 128 threads
  float m = 0.f;
  for (int c = 0; c < CH; ++c) m = fmaxf(m, Pmax[((size_t)g * CH + c) * 128 + f]);
  flat[g * 128 + f] = m;
}

extern "C" void kernel_launch(void* const* d_in, const int* in_sizes, int n_in,
                              void* d_out, int out_size, void* d_ws, size_t ws_size,
                              hipStream_t stream) {
  const float* inputs = (const float*)d_in[0];
  const int* eidx = (const int*)d_in[1];
  const int* batch = (const int*)d_in[2];
  const float* ew = (const float*)d_in[3];
  const float* Wg = (const float*)d_in[4];
  const float* bias = (const float*)d_in[5];
  const float* gw = (const float*)d_in[6];
  const float* gb = (const float*)d_in[7];
  const float* galpha = (const float*)d_in[8];

  int N = in_sizes[0] / 128;
  int E = in_sizes[1] / 2;
  const int* erow = eidx;       // edge_index[0] = source
  const int* ecol = eidx + E;   // edge_index[1] = target

  char* w = (char*)d_ws;
  auto alloc = [&](size_t bytes) {
    char* p = w;
    w += (bytes + 255) & ~(size_t)255;
    return p;
  };
  float* x = (float*)alloc((size_t)N * 128 * 4);
  float* deg = (float*)alloc((size_t)N * 4);
  float* dis = (float*)alloc((size_t)N * 4);
  int* ecnt = (int*)alloc((size_t)N * 4);
  int* off = (int*)alloc((size_t)(N + 1) * 4);
  int* cursor = (int*)alloc((size_t)N * 4);
  int* srow = (int*)alloc((size_t)E * 4);
  float* snorm = (float*)alloc((size_t)E * 4);
  int* gstart = (int*)alloc((size_t)(NUM_G + 1) * 4);
  float* Ssum = (float*)alloc((size_t)NUM_G * CH * 128 * 4);
  float* Ssq = (float*)alloc((size_t)NUM_G * CH * 128 * 4);
  float* Pmax = (float*)alloc((size_t)NUM_G * CH * 128 * 4);
  int NB = (N + 255) / 256;
  int* bsum = (int*)alloc((size_t)NB * 4);

  float* outh = (float*)d_out;             // h: N x 128
  float* flat = outh + (size_t)N * 128;    // flat: 64 x 128

  k_init<<<(N + 255) / 256, 256, 0, stream>>>(batch, deg, ecnt, gstart, N);
  k_deg<<<(E + 255) / 256, 256, 0, stream>>>(ecol, ew, deg, ecnt, E);
  k_scanA<<<NB, 256, 0, stream>>>(ecnt, bsum, N);
  k_scanB<<<1, 1024, 0, stream>>>(bsum, off, NB, N);
  k_scanC<<<NB, 256, 0, stream>>>(ecnt, bsum, deg, off, cursor, dis, N);
  k_gemm<<<(N + 63) / 64, 512, 0, stream>>>(inputs, Wg, x, N);
  k_scatter<<<(E + 255) / 256, 256, 0, stream>>>(erow, ecol, ew, dis, cursor, srow, snorm, E);
  k_accum<<<(N + 3) / 4, 256, 0, stream>>>(x, dis, off, srow, snorm, bias, outh, N);
  k_stats<<<NUM_G * CH, 256, 0, stream>>>(outh, gstart, Ssum, Ssq);
  k_final<<<NUM_G * CH, 256, 0, stream>>>(outh, gstart, Ssum, Ssq, galpha, gw, gb, Pmax);
  k_flat<<<NUM_G, 128, 0, stream>>>(Pmax, flat);
}